// Round 14
// baseline (248.840 us; speedup 1.0000x reference)
//
#include <hip/hip_runtime.h>

// ---------------------------------------------------------------------------
// VectorQuantizer R14: R8 exact structure, LDS shrunk for 4 blocks/CU.
// Ledger: R8 (64 rows/block, 512 blocks, LDS chunks, CAP=32) = 83us fused,
// 2 blocks/CU, all pipes idle (TLP-starved). R9 counted-vmcnt = null.
// R10-R13 (1024-block geometries) = 136-240us, regression unexplained ->
// abandoned. R14 changes ONE variable vs R8: candS CAP 32->5, cutting LDS
// 54272->~40448B so 4 blocks/CU fit (16 waves/CU, 4/SIMD). Overflow (n>CAP)
// now reachable but rare (P<<1%) and handled by the R8-verified bounded
// lane-parallel full scan (~3us).
// Exactness: unchanged from R8 -- candidates form a margin superset of the
// true argmin (MARGIN=0.25 >> 2*bf16 dot error); overflow rows use a full
// exact fp32 scan; all resolved with fp32 rescore + index tie-break.
// ---------------------------------------------------------------------------

constexpr int Mrows = 32768;
constexpr int Ddim  = 256;
constexpr int Kcode = 1024;

constexpr int   CAP    = 5;      // shrunk from 32: overflow -> bounded scan
constexpr float MARGIN = 0.25f;

typedef unsigned long long u64;
typedef unsigned short ushort_t;
typedef __attribute__((ext_vector_type(8))) short bf16x8;
typedef __attribute__((ext_vector_type(4))) float f32x4;

__device__ inline u64 packKey(float v, int idx) {
    unsigned u = __float_as_uint(v);
    u = (u & 0x80000000u) ? ~u : (u | 0x80000000u);   // order-preserving
    return ((u64)u << 32) | (unsigned)idx;
}
__device__ inline float unpackScore(u64 k) {
    unsigned v = (unsigned)(k >> 32);
    unsigned orig = (v & 0x80000000u) ? (v ^ 0x80000000u) : ~v;
    return __uint_as_float(orig);
}
__device__ inline ushort_t f2bf(float f) {   // RTN-even
    unsigned u = __float_as_uint(f);
    return (ushort_t)((u + 0x7fffu + ((u >> 16) & 1u)) >> 16);
}
__device__ inline void gload_lds16(const void* g, void* l) {
    __builtin_amdgcn_global_load_lds(
        (const __attribute__((address_space(1))) unsigned int*)g,
        (__attribute__((address_space(3))) unsigned int*)l, 16, 0, 0);
}

// ---- prep: block c handles codes [c*64, c*64+64)  (verified R4-R13) ----
__global__ __launch_bounds__(256)
void vq_prep(const float* __restrict__ E, float* __restrict__ ET,
             char* __restrict__ ETbf, float* __restrict__ norms) {
    __shared__ float tile[256][64];   // [k][code_local]
    const int t = threadIdx.x;
    const int c = blockIdx.x;

    #pragma unroll
    for (int i = 0; i < 16; ++i) {
        const int k = i * 16 + (t >> 4);
        *(float4*)&tile[k][(t & 15) * 4] =
            *(const float4*)&E[(size_t)k * Kcode + c * 64 + (t & 15) * 4];
    }
    __syncthreads();

    if (t < 64) {
        float s = 0.f;
        for (int k = 0; k < 256; ++k) s = fmaf(tile[k][t], tile[k][t], s);
        norms[c * 64 + t] = s;
    }
    #pragma unroll
    for (int j = 0; j < 16; ++j) {
        const int cl = t >> 2, k0 = (t & 3) * 64 + j * 4;
        float4 v = {tile[k0][cl], tile[k0 + 1][cl], tile[k0 + 2][cl], tile[k0 + 3][cl]};
        *(float4*)&ET[(size_t)(c * 64 + cl) * Ddim + k0] = v;
    }
    // ETbf fragment-linear: group G (16 codes) at byte G*8192 + s*1024 + l*16;
    // lane l: code = G*16 + (l&15), k = s*32 + (l>>4)*8 .. +8
    #pragma unroll
    for (int i = 0; i < 8; ++i) {
        const int wd = i * 256 + t;
        const int g = wd >> 9, s = (wd >> 6) & 7, l = wd & 63;
        const int cl = g * 16 + (l & 15);
        const int k0 = s * 32 + (l >> 4) * 8;
        union { uint4 v; ushort_t u[8]; } pk;
        #pragma unroll
        for (int j = 0; j < 8; ++j) pk.u[j] = f2bf(tile[k0 + j][cl]);
        *(uint4*)(ETbf + (size_t)c * 32768 + (size_t)wd * 16) = pk.v;
    }
}

// ---- fused: 64 rows x all 1024 codes per block; resolve in-block ----
__global__ __launch_bounds__(256, 2)
void vq_fused(const float* __restrict__ X, const char* __restrict__ ETbf,
              const float* __restrict__ ET, const float* __restrict__ norms,
              float* __restrict__ out, double* __restrict__ partials) {
    __shared__ __align__(16) char smB[2][16384];   // 32 codes x 256 dims bf16
    __shared__ float    nrmS[1024];
    __shared__ u64      candS[64][CAP];
    __shared__ int      cntS[64];
    __shared__ unsigned escS[64];
    __shared__ float    rowminS[64];
    __shared__ double   lred[4];
    // LDS total: 32768+4096+2560+256+256+256+32 = 40224 B -> 4 blocks/CU

    const int t = threadIdx.x;
    const int l = t & 63;
    const int w = t >> 6;
    const int l15 = l & 15, lq = l >> 4;
    const int row0 = blockIdx.x * 64;

    if (t < 64) { cntS[t] = 0; escS[t] = 0; }
    #pragma unroll
    for (int i = 0; i < 4; ++i) nrmS[i * 256 + t] = norms[i * 256 + t];

    // ---- A fragments: wave w owns rows [row0 + w*16, +16)  (32 VGPRs) ----
    bf16x8 afrag[8];
    #pragma unroll
    for (int s = 0; s < 8; ++s) {
        const float* xp = X + (size_t)(row0 + w * 16 + l15) * Ddim
                          + s * 32 + lq * 8;
        const float4 v0 = *(const float4*)xp;
        const float4 v1 = *(const float4*)(xp + 4);
        union { bf16x8 v; ushort_t u[8]; } pk;
        pk.u[0] = f2bf(v0.x); pk.u[1] = f2bf(v0.y);
        pk.u[2] = f2bf(v0.z); pk.u[3] = f2bf(v0.w);
        pk.u[4] = f2bf(v1.x); pk.u[5] = f2bf(v1.y);
        pk.u[6] = f2bf(v1.z); pk.u[7] = f2bf(v1.w);
        afrag[s] = pk.v;
    }

    // per-lane top-3 tracking (values; indices only for top-2)
    float b1v[4], b2v[4], b3v[4];
    int   b1i[4], b2i[4];
    #pragma unroll
    for (int r = 0; r < 4; ++r) {
        b1v[r] = 3.4e38f; b2v[r] = 3.4e38f; b3v[r] = 3.4e38f;
        b1i[r] = 0; b2i[r] = 0;
    }

    auto STAGE = [&](int c, int buf) {
        const char* src = ETbf + ((size_t)c << 14);
        #pragma unroll
        for (int i = 0; i < 4; ++i)
            gload_lds16(src + (size_t)((i * 256 + t) << 4),
                        smB[buf] + ((i * 256 + (t & ~63)) << 4));
    };

    auto COMPUTE = [&](int c, int buf) {
        #pragma unroll
        for (int g = 0; g < 2; ++g) {
            const char* base = smB[buf] + ((g * 8) * 64 + l) * 16;
            bf16x8 b[8];
            #pragma unroll
            for (int s = 0; s < 8; ++s) b[s] = *(const bf16x8*)(base + s * 1024);
            f32x4 a0 = {0.f, 0.f, 0.f, 0.f}, a1 = {0.f, 0.f, 0.f, 0.f};
            #pragma unroll
            for (int s = 0; s < 8; s += 2) {     // two independent chains
                a0 = __builtin_amdgcn_mfma_f32_16x16x32_bf16(afrag[s], b[s], a0, 0, 0, 0);
                a1 = __builtin_amdgcn_mfma_f32_16x16x32_bf16(afrag[s + 1], b[s + 1], a1, 0, 0, 0);
            }
            const int code = c * 32 + g * 16 + l15;
            const float nk = nrmS[code];
            #pragma unroll
            for (int r = 0; r < 4; ++r) {
                const float sc = fmaf(-2.f, a0[r] + a1[r], nk);
                if (sc < b1v[r]) {
                    b3v[r] = b2v[r]; b2v[r] = b1v[r]; b2i[r] = b1i[r];
                    b1v[r] = sc; b1i[r] = code;
                } else if (sc < b2v[r]) {
                    b3v[r] = b2v[r]; b2v[r] = sc; b2i[r] = code;
                } else if (sc < b3v[r]) {
                    b3v[r] = sc;
                }
            }
        }
    };

    // ---- chunk pipeline: 32 chunks of 32 codes, double-buffered ----
    STAGE(0, 0);
    __syncthreads();
    for (int c = 0; c < 32; ++c) {
        if (c < 31) STAGE(c + 1, (c + 1) & 1);
        COMPUTE(c, c & 1);
        __syncthreads();
    }

    // ---- emission with FINAL block threshold ----
    #pragma unroll
    for (int r = 0; r < 4; ++r) {
        float m = b1v[r];
        #pragma unroll
        for (int off = 1; off < 16; off <<= 1)
            m = fminf(m, __shfl_xor(m, off, 16));
        const int rowL = w * 16 + lq * 4 + r;
        if (l15 == 0) rowminS[rowL] = m;
        const float thr = m + MARGIN;
        if (b1v[r] <= thr) {
            const int p = atomicAdd(&cntS[rowL], 1);
            if (p < CAP) candS[rowL][p] = packKey(b1v[r], b1i[r]);
        }
        if (b2v[r] <= thr) {
            const int p = atomicAdd(&cntS[rowL], 1);
            if (p < CAP) candS[rowL][p] = packKey(b2v[r], b2i[r]);
        }
        if (b3v[r] <= thr)
            atomicOr(&escS[rowL], 1u << l15);   // lane may have dropped a 4th+
    }
    __syncthreads();

    // ---- resolve epilogue: wave handles its own 16 rows ----
    double lacc = 0.0;
    for (int rr = 0; rr < 16; ++rr) {
        const int rowL = w * 16 + rr;
        const int row = row0 + rowL;
        const float4 x4 = *(const float4*)&X[(size_t)row * Ddim + l * 4];
        const int n = cntS[rowL];
        const unsigned em = escS[rowL];

        // shuffle-parallel exact fp32 rescore (one code, all 64 lanes)
        auto rescoreS = [&](int code) -> float {
            const float4 e4 = *(const float4*)&ET[(size_t)code * Ddim + l * 4];
            float d = x4.x * e4.x;
            d = fmaf(x4.y, e4.y, d);
            d = fmaf(x4.z, e4.z, d);
            d = fmaf(x4.w, e4.w, d);
            #pragma unroll
            for (int off = 1; off < 64; off <<= 1) d += __shfl_xor(d, off, 64);
            return nrmS[code] - 2.f * d;
        };
        // per-lane serial exact fp32 score (lane-parallel over codes)
        auto laneDot = [&](int cd) -> float {
            const float* ep = ET + (size_t)cd * Ddim;
            const float* xp = X + (size_t)row * Ddim;
            float s0 = 0.f, s1 = 0.f, s2 = 0.f, s3 = 0.f;
            for (int d0 = 0; d0 < 64; ++d0) {
                const float4 e4 = *(const float4*)(ep + d0 * 4);
                const float4 xx = *(const float4*)(xp + d0 * 4);
                s0 = fmaf(xx.x, e4.x, s0); s1 = fmaf(xx.y, e4.y, s1);
                s2 = fmaf(xx.z, e4.z, s2); s3 = fmaf(xx.w, e4.w, s3);
            }
            return nrmS[cd] - 2.f * ((s0 + s1) + (s2 + s3));
        };

        int code;
        if (n == 1 && em == 0) {
            code = (int)(candS[rowL][0] & 0xffffffffu);   // provably the argmin
        } else if (n >= 1 && n <= CAP) {
            float bS = 3.4e38f; int bC = 0x7fffffff;
            for (int j = 0; j < n; ++j) {
                const int cd = (int)(candS[rowL][j] & 0xffffffffu);
                const float s = rescoreS(cd);
                if (s < bS || (s == bS && cd < bC)) { bS = s; bC = cd; }
            }
            unsigned m2 = em;
            while (m2) {   // escalated lane: rescan its 64 codes, lane-parallel
                const int c15 = __ffs(m2) - 1; m2 &= m2 - 1;
                const int cd = l * 16 + c15;
                u64 k = packKey(laneDot(cd), cd);
                #pragma unroll
                for (int off = 1; off < 64; off <<= 1) {
                    const u64 o = __shfl_xor(k, off, 64);
                    if (o < k) k = o;
                }
                const float s = unpackScore(k);
                const int cd2 = (int)(k & 0xffffffffu);
                if (s < bS || (s == bS && cd2 < bC)) { bS = s; bC = cd2; }
            }
            code = bC;
        } else {   // overflow (rare, P<<1%): bounded lane-parallel full scan
            u64 k = ~0ULL;
            for (int i = 0; i < 16; ++i) {
                const int cd = i * 64 + l;
                const u64 k2 = packKey(laneDot(cd), cd);
                if (k2 < k) k = k2;
            }
            #pragma unroll
            for (int off = 1; off < 64; off <<= 1) {
                const u64 o = __shfl_xor(k, off, 64);
                if (o < k) k = o;
            }
            code = (int)(k & 0xffffffffu);
        }

        const float4 q4 = *(const float4*)&ET[(size_t)code * Ddim + l * 4];
        *(float4*)&out[(size_t)row * Ddim + l * 4] = q4;
        const double dx = (double)(q4.x - x4.x), dy = (double)(q4.y - x4.y);
        const double dz = (double)(q4.z - x4.z), dw = (double)(q4.w - x4.w);
        lacc += dx * dx + dy * dy + dz * dz + dw * dw;
    }
    #pragma unroll
    for (int off = 32; off; off >>= 1) lacc += __shfl_down(lacc, off, 64);
    if (l == 0) lred[w] = lacc;
    __syncthreads();
    if (t == 0)
        partials[blockIdx.x] = lred[0] + lred[1] + lred[2] + lred[3];
}

// ---- final loss ----
__global__ __launch_bounds__(256)
void vq_lossk(const double* __restrict__ partials, float* __restrict__ lossOut) {
    __shared__ double red[4];
    double v = 0.0;
    for (int i = threadIdx.x; i < 512; i += 256) v += partials[i];
    #pragma unroll
    for (int off = 32; off; off >>= 1) v += __shfl_down(v, off, 64);
    const int lane = threadIdx.x & 63, grp = threadIdx.x >> 6;
    if (lane == 0) red[grp] = v;
    __syncthreads();
    if (threadIdx.x == 0)
        lossOut[0] = (float)(1.25 * (red[0] + red[1] + red[2] + red[3]) /
                             (double)((size_t)Mrows * Ddim));
}

// ===========================================================================
extern "C" void kernel_launch(void* const* d_in, const int* in_sizes, int n_in,
                              void* d_out, int out_size, void* d_ws, size_t ws_size,
                              hipStream_t stream) {
    const float* X = (const float*)d_in[0];
    const float* E = (const float*)d_in[1];
    float* out = (float*)d_out;
    char* ws = (char*)d_ws;

    // workspace: partials 4KB | ET 1MB | ETbf 512KB | norms 4KB  (~1.5MB)
    const size_t partB = 512 * 8;
    const size_t etB   = (size_t)Kcode * Ddim * 4;
    const size_t etbfB = (size_t)Kcode * Ddim * 2;
    char* p = ws;
    double* partials = (double*)p;  p += partB;
    float*  ET       = (float*)p;   p += etB;
    char*   ETbf     = p;           p += etbfB;
    float*  norms    = (float*)p;

    vq_prep<<<16, 256, 0, stream>>>(E, ET, ETbf, norms);
    vq_fused<<<Mrows / 64, 256, 0, stream>>>(X, ETbf, ET, norms, out, partials);
    vq_lossk<<<1, 256, 0, stream>>>(partials, out + (size_t)Mrows * Ddim);
}

// Round 15
// 176.113 us; speedup vs baseline: 1.4130x; 1.4130x over previous
//
#include <hip/hip_runtime.h>

// ---------------------------------------------------------------------------
// VectorQuantizer R15: R8 shell (512 blocks x 64 rows, 2 blk/CU — the only
// geometry measured fast) with 32x32x16 MFMA so each wave covers 32 rows:
// B-fragment LDS traffic per row HALVES (per-CU ds_read floor ~20 -> ~10us).
// Block = 4 waves: (row-group rg 0/1 x 32 rows) x (code-split s2 0/1 x 512).
// 16 phases: stage chunk p (split0) + chunk 16+p (split1), 32KB, 2-buf.
// Chunk = 32 codes x K=256 (full dot per phase). Tracking: top-2 + b2-
// escalation per row-slot (R5/R6-verified); resolve in-block with FINAL
// threshold, all fallbacks lane-parallel bounded (R8-verified).
// C/D mapping (HW-verified m74/m101): col=lane&31, row=(j&3)+8*(j>>2)+4*(l>>5).
// A/B mapping: row/col = l&31, k = (l>>5)*8 + 0..7 (32-wide analog of the
// 16x16 mapping verified R3-R8).
// Exactness: MARGIN=0.25 >> 2*bf16-dot-error; per (col,split) lane: if b2
// within thr -> escalate (rescan its 16 codes in fp32); else push b1; final
// filter + exact fp32 rescore with index tie-break; overflow -> full scan.
// ---------------------------------------------------------------------------

constexpr int Mrows = 32768;
constexpr int Ddim  = 256;
constexpr int Kcode = 1024;

constexpr int   CAP    = 8;
constexpr float MARGIN = 0.25f;

typedef unsigned long long u64;
typedef unsigned short ushort_t;
typedef __attribute__((ext_vector_type(8))) short bf16x8;
typedef __attribute__((ext_vector_type(16))) float f32x16;

__device__ inline u64 packKey(float v, int idx) {
    unsigned u = __float_as_uint(v);
    u = (u & 0x80000000u) ? ~u : (u | 0x80000000u);   // order-preserving
    return ((u64)u << 32) | (unsigned)idx;
}
__device__ inline float unpackScore(u64 k) {
    unsigned v = (unsigned)(k >> 32);
    unsigned orig = (v & 0x80000000u) ? (v ^ 0x80000000u) : ~v;
    return __uint_as_float(orig);
}
__device__ inline ushort_t f2bf(float f) {   // RTN-even
    unsigned u = __float_as_uint(f);
    return (ushort_t)((u + 0x7fffu + ((u >> 16) & 1u)) >> 16);
}
__device__ inline void gload_lds16(const void* g, void* l) {
    __builtin_amdgcn_global_load_lds(
        (const __attribute__((address_space(1))) unsigned int*)g,
        (__attribute__((address_space(3))) unsigned int*)l, 16, 0, 0);
}

// ---- prep: block c handles codes [c*64, c*64+64) ----
// ETbf layout for 32x32x16: 32-code tile T at byte T*16384; word wd within
// tile = ks*64 + l (ks=0..15, l=lane): lane l holds code T*32+(l&31),
// k = ks*16 + (l>>5)*8 .. +8  (16B).
__global__ __launch_bounds__(256)
void vq_prep(const float* __restrict__ E, float* __restrict__ ET,
             char* __restrict__ ETbf, float* __restrict__ norms) {
    __shared__ float tile[256][64];   // [k][code_local]
    const int t = threadIdx.x;
    const int c = blockIdx.x;

    #pragma unroll
    for (int i = 0; i < 16; ++i) {
        const int k = i * 16 + (t >> 4);
        *(float4*)&tile[k][(t & 15) * 4] =
            *(const float4*)&E[(size_t)k * Kcode + c * 64 + (t & 15) * 4];
    }
    __syncthreads();

    if (t < 64) {
        float s = 0.f;
        for (int k = 0; k < 256; ++k) s = fmaf(tile[k][t], tile[k][t], s);
        norms[c * 64 + t] = s;
    }
    #pragma unroll
    for (int j = 0; j < 16; ++j) {
        const int cl = t >> 2, k0 = (t & 3) * 64 + j * 4;
        float4 v = {tile[k0][cl], tile[k0 + 1][cl], tile[k0 + 2][cl], tile[k0 + 3][cl]};
        *(float4*)&ET[(size_t)(c * 64 + cl) * Ddim + k0] = v;
    }
    // new fragment-linear layout (2048 words per prep block)
    #pragma unroll
    for (int i = 0; i < 8; ++i) {
        const int wd = i * 256 + t;          // 0..2047
        const int g2 = wd >> 10;             // col-tile 0/1
        const int ks = (wd >> 6) & 15;
        const int l  = wd & 63;
        const int cl = g2 * 32 + (l & 31);
        const int k0 = ks * 16 + (l >> 5) * 8;
        union { uint4 v; ushort_t u[8]; } pk;
        #pragma unroll
        for (int j = 0; j < 8; ++j) pk.u[j] = f2bf(tile[k0 + j][cl]);
        *(uint4*)(ETbf + (size_t)c * 32768 + (size_t)wd * 16) = pk.v;
    }
}

// ---- fused: 64 rows x 1024 codes/block; 32x32x16 MFMA scoring ----
__global__ __launch_bounds__(256, 2)
void vq_fused(const float* __restrict__ X, const char* __restrict__ ETbf,
              const float* __restrict__ ET, const float* __restrict__ norms,
              float* __restrict__ out, double* __restrict__ partials) {
    __shared__ __align__(16) char smB[2][32768];   // 2 bufs x (2 splits x 16KB)
    __shared__ float    nrmS[1024];
    __shared__ u64      candS[64][CAP];
    __shared__ int      cntS[64];
    __shared__ unsigned escS[64][2];
    __shared__ float    rowminS[64][2];
    __shared__ double   lred[4];

    const int t = threadIdx.x;
    const int l = t & 63;
    const int w = t >> 6;
    const int rg = w >> 1;          // row-group 0/1 (32 rows each)
    const int s2 = w & 1;           // code-split 0/1 (512 codes each)
    const int l31 = l & 31, lh = l >> 5;
    const int row0 = blockIdx.x * 64;
    const int row0w = row0 + rg * 32;

    if (t < 64) { cntS[t] = 0; escS[t][0] = 0; escS[t][1] = 0; }
    #pragma unroll
    for (int i = 0; i < 4; ++i) nrmS[i * 256 + t] = norms[i * 256 + t];

    // ---- A fragments: 32 rows x K=256; lane: row=l&31, k=ks*16+(l>>5)*8 ----
    bf16x8 afrag[16];
    #pragma unroll
    for (int ks = 0; ks < 16; ++ks) {
        const float* xp = X + (size_t)(row0w + l31) * Ddim + ks * 16 + lh * 8;
        const float4 v0 = *(const float4*)xp;
        const float4 v1 = *(const float4*)(xp + 4);
        union { bf16x8 v; ushort_t u[8]; } pk;
        pk.u[0] = f2bf(v0.x); pk.u[1] = f2bf(v0.y);
        pk.u[2] = f2bf(v0.z); pk.u[3] = f2bf(v0.w);
        pk.u[4] = f2bf(v1.x); pk.u[5] = f2bf(v1.y);
        pk.u[6] = f2bf(v1.z); pk.u[7] = f2bf(v1.w);
        afrag[ks] = pk.v;
    }

    // per-lane top-2 per row-slot j (16 slots; lane's col fixed per phase)
    float b1v[16], b2v[16];
    short b1i[16];
    #pragma unroll
    for (int j = 0; j < 16; ++j) { b1v[j] = 3.4e38f; b2v[j] = 3.4e38f; b1i[j] = 0; }

    auto STAGE = [&](int p, int buf) {
        #pragma unroll
        for (int i = 0; i < 8; ++i) {
            const int ch = (i < 4) ? p : (16 + p);
            const char* src = ETbf + ((size_t)ch << 14) + (((i & 3) * 256 + t) << 4);
            gload_lds16(src, smB[buf] + ((i * 256 + (t & ~63)) << 4));
        }
    };

    auto COMPUTE = [&](int p, int buf) {
        const char* base = smB[buf] + s2 * 16384 + l * 16;
        bf16x8 b[16];
        #pragma unroll
        for (int ks = 0; ks < 16; ++ks) b[ks] = *(const bf16x8*)(base + ks * 1024);
        f32x16 acc = {};
        #pragma unroll
        for (int ks = 0; ks < 16; ++ks)
            acc = __builtin_amdgcn_mfma_f32_32x32x16_bf16(afrag[ks], b[ks], acc, 0, 0, 0);
        const int code = (s2 * 16 + p) * 32 + l31;
        const float nk = nrmS[code];
        #pragma unroll
        for (int j = 0; j < 16; ++j) {
            const float sc = fmaf(-2.f, acc[j], nk);
            if (sc < b1v[j]) { b2v[j] = b1v[j]; b1v[j] = sc; b1i[j] = (short)code; }
            else             { b2v[j] = fminf(b2v[j], sc); }
        }
    };

    // ---- pipeline: 16 phases, 32 codes/split each, double-buffered ----
    STAGE(0, 0);
    __syncthreads();
    for (int p = 0; p < 16; ++p) {
        if (p < 15) STAGE(p + 1, (p + 1) & 1);
        COMPUTE(p, p & 1);
        __syncthreads();
    }

    // ---- emission: row-min over 32 cols; push b1 / escalate on b2 ----
    #pragma unroll
    for (int j = 0; j < 16; ++j) {
        float m = b1v[j];
        #pragma unroll
        for (int off = 1; off < 32; off <<= 1)
            m = fminf(m, __shfl_xor(m, off, 32));     // within 32-lane half
        const int rowL = rg * 32 + (j & 3) + 8 * (j >> 2) + 4 * lh;
        if (l31 == 0) rowminS[rowL][s2] = m;
        const float thr = m + MARGIN;
        if (b2v[j] <= thr) {
            atomicOr(&escS[rowL][s2], 1u << l31);     // may have dropped a 3rd
        } else if (b1v[j] <= thr) {
            const int p = atomicAdd(&cntS[rowL], 1);
            if (p < CAP) candS[rowL][p] = packKey(b1v[j], (int)b1i[j]);
        }
    }
    __syncthreads();

    // ---- resolve: wave handles 16 rows; FINAL threshold; bounded paths ----
    double lacc = 0.0;
    for (int rr = 0; rr < 16; ++rr) {
        const int rowL = w * 16 + rr;
        const int row = row0 + rowL;
        const float4 x4 = *(const float4*)&X[(size_t)row * Ddim + l * 4];
        const float thrF = fminf(rowminS[rowL][0], rowminS[rowL][1]) + MARGIN;
        const int n = cntS[rowL];
        const unsigned em0 = escS[rowL][0], em1 = escS[rowL][1];

        auto rescoreS = [&](int code) -> float {
            const float4 e4 = *(const float4*)&ET[(size_t)code * Ddim + l * 4];
            float d = x4.x * e4.x;
            d = fmaf(x4.y, e4.y, d);
            d = fmaf(x4.z, e4.z, d);
            d = fmaf(x4.w, e4.w, d);
            #pragma unroll
            for (int off = 1; off < 64; off <<= 1) d += __shfl_xor(d, off, 64);
            return nrmS[code] - 2.f * d;
        };
        auto laneDot = [&](int cd) -> float {
            const float* ep = ET + (size_t)cd * Ddim;
            const float* xp = X + (size_t)row * Ddim;
            float s0 = 0.f, s1 = 0.f, s2_ = 0.f, s3 = 0.f;
            for (int d0 = 0; d0 < 64; ++d0) {
                const float4 e4 = *(const float4*)(ep + d0 * 4);
                const float4 xx = *(const float4*)(xp + d0 * 4);
                s0 = fmaf(xx.x, e4.x, s0); s1 = fmaf(xx.y, e4.y, s1);
                s2_ = fmaf(xx.z, e4.z, s2_); s3 = fmaf(xx.w, e4.w, s3);
            }
            return nrmS[cd] - 2.f * ((s0 + s1) + (s2_ + s3));
        };

        int code;
        if (n > CAP) {
            // bounded lane-parallel full fp32 scan (rare)
            u64 k = ~0ULL;
            for (int i = 0; i < 16; ++i) {
                const int cd = i * 64 + l;
                const u64 k2 = packKey(laneDot(cd), cd);
                if (k2 < k) k = k2;
            }
            #pragma unroll
            for (int off = 1; off < 64; off <<= 1) {
                const u64 o = __shfl_xor(k, off, 64);
                if (o < k) k = o;
            }
            code = (int)(k & 0xffffffffu);
        } else {
            int kept = 0, only = -1;
            for (int j = 0; j < n; ++j) {
                const u64 key = candS[rowL][j];
                if (unpackScore(key) <= thrF) { only = (int)(key & 0xffffffffu); ++kept; }
            }
            if (kept == 1 && em0 == 0 && em1 == 0) {
                code = only;    // provably the argmin
            } else {
                float bS = 3.4e38f; int bC = 0x7fffffff;
                for (int j = 0; j < n; ++j) {
                    const u64 key = candS[rowL][j];
                    if (unpackScore(key) > thrF) continue;
                    const int cd = (int)(key & 0xffffffffu);
                    const float s = rescoreS(cd);
                    if (s < bS || (s == bS && cd < bC)) { bS = s; bC = cd; }
                }
                #pragma unroll
                for (int sp = 0; sp < 2; ++sp) {
                    unsigned m2 = sp ? em1 : em0;
                    while (m2) {   // esc (col,split): 16 codes, lane-parallel
                        const int col = __ffs(m2) - 1; m2 &= m2 - 1;
                        u64 k = ~0ULL;
                        if (l < 16) {
                            const int cd = sp * 512 + l * 32 + col;
                            k = packKey(laneDot(cd), cd);
                        }
                        #pragma unroll
                        for (int off = 1; off < 64; off <<= 1) {
                            const u64 o = __shfl_xor(k, off, 64);
                            if (o < k) k = o;
                        }
                        const float s = unpackScore(k);
                        const int cd2 = (int)(k & 0xffffffffu);
                        if (s < bS || (s == bS && cd2 < bC)) { bS = s; bC = cd2; }
                    }
                }
                code = bC;
            }
        }

        const float4 q4 = *(const float4*)&ET[(size_t)code * Ddim + l * 4];
        *(float4*)&out[(size_t)row * Ddim + l * 4] = q4;
        const double dx = (double)(q4.x - x4.x), dy = (double)(q4.y - x4.y);
        const double dz = (double)(q4.z - x4.z), dw = (double)(q4.w - x4.w);
        lacc += dx * dx + dy * dy + dz * dz + dw * dw;
    }
    #pragma unroll
    for (int off = 32; off; off >>= 1) lacc += __shfl_down(lacc, off, 64);
    if (l == 0) lred[w] = lacc;
    __syncthreads();
    if (t == 0)
        partials[blockIdx.x] = lred[0] + lred[1] + lred[2] + lred[3];
}

// ---- final loss ----
__global__ __launch_bounds__(256)
void vq_lossk(const double* __restrict__ partials, float* __restrict__ lossOut) {
    __shared__ double red[4];
    double v = 0.0;
    for (int i = threadIdx.x; i < 512; i += 256) v += partials[i];
    #pragma unroll
    for (int off = 32; off; off >>= 1) v += __shfl_down(v, off, 64);
    const int lane = threadIdx.x & 63, grp = threadIdx.x >> 6;
    if (lane == 0) red[grp] = v;
    __syncthreads();
    if (threadIdx.x == 0)
        lossOut[0] = (float)(1.25 * (red[0] + red[1] + red[2] + red[3]) /
                             (double)((size_t)Mrows * Ddim));
}

// ===========================================================================
extern "C" void kernel_launch(void* const* d_in, const int* in_sizes, int n_in,
                              void* d_out, int out_size, void* d_ws, size_t ws_size,
                              hipStream_t stream) {
    const float* X = (const float*)d_in[0];
    const float* E = (const float*)d_in[1];
    float* out = (float*)d_out;
    char* ws = (char*)d_ws;

    const size_t partB = 512 * 8;
    const size_t etB   = (size_t)Kcode * Ddim * 4;
    const size_t etbfB = (size_t)Kcode * Ddim * 2;
    char* p = ws;
    double* partials = (double*)p;  p += partB;
    float*  ET       = (float*)p;   p += etB;
    char*   ETbf     = p;           p += etbfB;
    float*  norms    = (float*)p;

    vq_prep<<<16, 256, 0, stream>>>(E, ET, ETbf, norms);
    vq_fused<<<Mrows / 64, 256, 0, stream>>>(X, ETbf, ET, norms, out, partials);
    vq_lossk<<<1, 256, 0, stream>>>(partials, out + (size_t)Mrows * Ddim);
}

// Round 16
// 88.944 us; speedup vs baseline: 2.7977x; 1.9800x over previous
//
#include <hip/hip_runtime.h>

// ---------------------------------------------------------------------------
// VectorQuantizer R16 == R8 VERBATIM (control / revert).
// R8 measured: total 88.96us, vq_fused 83us, occ 18.8%, VGPR 88, LDS 54272.
// R11-R15 (occupancy, pipeline, geometry, MFMA-shape levers) all regressed
// or were null; R14 (CAP-only delta) regressed 3x with no constructible
// mechanism -> this round re-measures R8 exactly to test environment drift.
// ---------------------------------------------------------------------------

constexpr int Mrows = 32768;
constexpr int Ddim  = 256;
constexpr int Kcode = 1024;

constexpr int   CAP    = 32;     // == 16 lanes x 2 pushes: cannot overflow
constexpr float MARGIN = 0.25f;

typedef unsigned long long u64;
typedef unsigned short ushort_t;
typedef __attribute__((ext_vector_type(8))) short bf16x8;
typedef __attribute__((ext_vector_type(4))) float f32x4;

__device__ inline u64 packKey(float v, int idx) {
    unsigned u = __float_as_uint(v);
    u = (u & 0x80000000u) ? ~u : (u | 0x80000000u);   // order-preserving
    return ((u64)u << 32) | (unsigned)idx;
}
__device__ inline float unpackScore(u64 k) {
    unsigned v = (unsigned)(k >> 32);
    unsigned orig = (v & 0x80000000u) ? (v ^ 0x80000000u) : ~v;
    return __uint_as_float(orig);
}
__device__ inline ushort_t f2bf(float f) {   // RTN-even
    unsigned u = __float_as_uint(f);
    return (ushort_t)((u + 0x7fffu + ((u >> 16) & 1u)) >> 16);
}
__device__ inline void gload_lds16(const void* g, void* l) {
    __builtin_amdgcn_global_load_lds(
        (const __attribute__((address_space(1))) unsigned int*)g,
        (__attribute__((address_space(3))) unsigned int*)l, 16, 0, 0);
}

// ---- prep: block c handles codes [c*64, c*64+64) ----
__global__ __launch_bounds__(256)
void vq_prep(const float* __restrict__ E, float* __restrict__ ET,
             char* __restrict__ ETbf, float* __restrict__ norms) {
    __shared__ float tile[256][64];   // [k][code_local]
    const int t = threadIdx.x;
    const int c = blockIdx.x;

    #pragma unroll
    for (int i = 0; i < 16; ++i) {
        const int k = i * 16 + (t >> 4);
        *(float4*)&tile[k][(t & 15) * 4] =
            *(const float4*)&E[(size_t)k * Kcode + c * 64 + (t & 15) * 4];
    }
    __syncthreads();

    if (t < 64) {
        float s = 0.f;
        for (int k = 0; k < 256; ++k) s = fmaf(tile[k][t], tile[k][t], s);
        norms[c * 64 + t] = s;
    }
    #pragma unroll
    for (int j = 0; j < 16; ++j) {
        const int cl = t >> 2, k0 = (t & 3) * 64 + j * 4;
        float4 v = {tile[k0][cl], tile[k0 + 1][cl], tile[k0 + 2][cl], tile[k0 + 3][cl]};
        *(float4*)&ET[(size_t)(c * 64 + cl) * Ddim + k0] = v;
    }
    // ETbf fragment-linear: group G (16 codes) at byte G*8192 + s*1024 + l*16;
    // lane l: code = G*16 + (l&15), k = s*32 + (l>>4)*8 .. +8
    #pragma unroll
    for (int i = 0; i < 8; ++i) {
        const int wd = i * 256 + t;
        const int g = wd >> 9, s = (wd >> 6) & 7, l = wd & 63;
        const int cl = g * 16 + (l & 15);
        const int k0 = s * 32 + (l >> 4) * 8;
        union { uint4 v; ushort_t u[8]; } pk;
        #pragma unroll
        for (int j = 0; j < 8; ++j) pk.u[j] = f2bf(tile[k0 + j][cl]);
        *(uint4*)(ETbf + (size_t)c * 32768 + (size_t)wd * 16) = pk.v;
    }
}

// ---- fused: 64 rows x all 1024 codes per block; resolve in-block ----
__global__ __launch_bounds__(256, 2)
void vq_fused(const float* __restrict__ X, const char* __restrict__ ETbf,
              const float* __restrict__ ET, const float* __restrict__ norms,
              float* __restrict__ out, double* __restrict__ partials) {
    __shared__ __align__(16) char smB[2][16384];   // 32 codes x 256 dims bf16
    __shared__ float    nrmS[1024];
    __shared__ u64      candS[64][CAP];
    __shared__ int      cntS[64];
    __shared__ unsigned escS[64];
    __shared__ float    rowminS[64];
    __shared__ double   lred[4];

    const int t = threadIdx.x;
    const int l = t & 63;
    const int w = t >> 6;
    const int l15 = l & 15, lq = l >> 4;
    const int row0 = blockIdx.x * 64;

    if (t < 64) { cntS[t] = 0; escS[t] = 0; }
    #pragma unroll
    for (int i = 0; i < 4; ++i) nrmS[i * 256 + t] = norms[i * 256 + t];

    // ---- A fragments: wave w owns rows [row0 + w*16, +16)  (32 VGPRs) ----
    bf16x8 afrag[8];
    #pragma unroll
    for (int s = 0; s < 8; ++s) {
        const float* xp = X + (size_t)(row0 + w * 16 + l15) * Ddim
                          + s * 32 + lq * 8;
        const float4 v0 = *(const float4*)xp;
        const float4 v1 = *(const float4*)(xp + 4);
        union { bf16x8 v; ushort_t u[8]; } pk;
        pk.u[0] = f2bf(v0.x); pk.u[1] = f2bf(v0.y);
        pk.u[2] = f2bf(v0.z); pk.u[3] = f2bf(v0.w);
        pk.u[4] = f2bf(v1.x); pk.u[5] = f2bf(v1.y);
        pk.u[6] = f2bf(v1.z); pk.u[7] = f2bf(v1.w);
        afrag[s] = pk.v;
    }

    // per-lane top-3 tracking (values; indices only for top-2)
    float b1v[4], b2v[4], b3v[4];
    int   b1i[4], b2i[4];
    #pragma unroll
    for (int r = 0; r < 4; ++r) {
        b1v[r] = 3.4e38f; b2v[r] = 3.4e38f; b3v[r] = 3.4e38f;
        b1i[r] = 0; b2i[r] = 0;
    }

    auto STAGE = [&](int c, int buf) {
        const char* src = ETbf + ((size_t)c << 14);
        #pragma unroll
        for (int i = 0; i < 4; ++i)
            gload_lds16(src + (size_t)((i * 256 + t) << 4),
                        smB[buf] + ((i * 256 + (t & ~63)) << 4));
    };

    auto COMPUTE = [&](int c, int buf) {
        #pragma unroll
        for (int g = 0; g < 2; ++g) {
            const char* base = smB[buf] + ((g * 8) * 64 + l) * 16;
            bf16x8 b[8];
            #pragma unroll
            for (int s = 0; s < 8; ++s) b[s] = *(const bf16x8*)(base + s * 1024);
            f32x4 a0 = {0.f, 0.f, 0.f, 0.f}, a1 = {0.f, 0.f, 0.f, 0.f};
            #pragma unroll
            for (int s = 0; s < 8; s += 2) {     // two independent chains
                a0 = __builtin_amdgcn_mfma_f32_16x16x32_bf16(afrag[s], b[s], a0, 0, 0, 0);
                a1 = __builtin_amdgcn_mfma_f32_16x16x32_bf16(afrag[s + 1], b[s + 1], a1, 0, 0, 0);
            }
            const int code = c * 32 + g * 16 + l15;
            const float nk = nrmS[code];
            #pragma unroll
            for (int r = 0; r < 4; ++r) {
                const float sc = fmaf(-2.f, a0[r] + a1[r], nk);
                if (sc < b1v[r]) {
                    b3v[r] = b2v[r]; b2v[r] = b1v[r]; b2i[r] = b1i[r];
                    b1v[r] = sc; b1i[r] = code;
                } else if (sc < b2v[r]) {
                    b3v[r] = b2v[r]; b2v[r] = sc; b2i[r] = code;
                } else if (sc < b3v[r]) {
                    b3v[r] = sc;
                }
            }
        }
    };

    // ---- chunk pipeline: 32 chunks of 32 codes, double-buffered ----
    STAGE(0, 0);
    __syncthreads();
    for (int c = 0; c < 32; ++c) {
        if (c < 31) STAGE(c + 1, (c + 1) & 1);
        COMPUTE(c, c & 1);
        __syncthreads();
    }

    // ---- emission with FINAL block threshold ----
    #pragma unroll
    for (int r = 0; r < 4; ++r) {
        float m = b1v[r];
        #pragma unroll
        for (int off = 1; off < 16; off <<= 1)
            m = fminf(m, __shfl_xor(m, off, 16));
        const int rowL = w * 16 + lq * 4 + r;
        if (l15 == 0) rowminS[rowL] = m;
        const float thr = m + MARGIN;
        if (b1v[r] <= thr) {
            const int p = atomicAdd(&cntS[rowL], 1);
            if (p < CAP) candS[rowL][p] = packKey(b1v[r], b1i[r]);
        }
        if (b2v[r] <= thr) {
            const int p = atomicAdd(&cntS[rowL], 1);
            if (p < CAP) candS[rowL][p] = packKey(b2v[r], b2i[r]);
        }
        if (b3v[r] <= thr)
            atomicOr(&escS[rowL], 1u << l15);   // lane may have dropped a 4th+
    }
    __syncthreads();

    // ---- resolve epilogue: wave handles its own 16 rows ----
    double lacc = 0.0;
    for (int rr = 0; rr < 16; ++rr) {
        const int rowL = w * 16 + rr;
        const int row = row0 + rowL;
        const float4 x4 = *(const float4*)&X[(size_t)row * Ddim + l * 4];
        const int n = cntS[rowL];
        const unsigned em = escS[rowL];

        // shuffle-parallel exact fp32 rescore (one code, all 64 lanes)
        auto rescoreS = [&](int code) -> float {
            const float4 e4 = *(const float4*)&ET[(size_t)code * Ddim + l * 4];
            float d = x4.x * e4.x;
            d = fmaf(x4.y, e4.y, d);
            d = fmaf(x4.z, e4.z, d);
            d = fmaf(x4.w, e4.w, d);
            #pragma unroll
            for (int off = 1; off < 64; off <<= 1) d += __shfl_xor(d, off, 64);
            return nrmS[code] - 2.f * d;
        };
        // per-lane serial exact fp32 score (lane-parallel over codes)
        auto laneDot = [&](int cd) -> float {
            const float* ep = ET + (size_t)cd * Ddim;
            const float* xp = X + (size_t)row * Ddim;
            float s0 = 0.f, s1 = 0.f, s2 = 0.f, s3 = 0.f;
            for (int d0 = 0; d0 < 64; ++d0) {
                const float4 e4 = *(const float4*)(ep + d0 * 4);
                const float4 xx = *(const float4*)(xp + d0 * 4);
                s0 = fmaf(xx.x, e4.x, s0); s1 = fmaf(xx.y, e4.y, s1);
                s2 = fmaf(xx.z, e4.z, s2); s3 = fmaf(xx.w, e4.w, s3);
            }
            return nrmS[cd] - 2.f * ((s0 + s1) + (s2 + s3));
        };

        int code;
        if (n == 1 && em == 0) {
            code = (int)(candS[rowL][0] & 0xffffffffu);   // provably the argmin
        } else if (n >= 1 && n <= CAP) {
            float bS = 3.4e38f; int bC = 0x7fffffff;
            for (int j = 0; j < n; ++j) {
                const int cd = (int)(candS[rowL][j] & 0xffffffffu);
                const float s = rescoreS(cd);
                if (s < bS || (s == bS && cd < bC)) { bS = s; bC = cd; }
            }
            unsigned m2 = em;
            while (m2) {   // escalated lane: rescan its 64 codes, lane-parallel
                const int c15 = __ffs(m2) - 1; m2 &= m2 - 1;
                const int cd = l * 16 + c15;
                u64 k = packKey(laneDot(cd), cd);
                #pragma unroll
                for (int off = 1; off < 64; off <<= 1) {
                    const u64 o = __shfl_xor(k, off, 64);
                    if (o < k) k = o;
                }
                const float s = unpackScore(k);
                const int cd2 = (int)(k & 0xffffffffu);
                if (s < bS || (s == bS && cd2 < bC)) { bS = s; bC = cd2; }
            }
            code = bC;
        } else {   // unreachable (CAP structural); cheap lane-parallel scan
            u64 k = ~0ULL;
            for (int i = 0; i < 16; ++i) {
                const int cd = i * 64 + l;
                const u64 k2 = packKey(laneDot(cd), cd);
                if (k2 < k) k = k2;
            }
            #pragma unroll
            for (int off = 1; off < 64; off <<= 1) {
                const u64 o = __shfl_xor(k, off, 64);
                if (o < k) k = o;
            }
            code = (int)(k & 0xffffffffu);
        }

        const float4 q4 = *(const float4*)&ET[(size_t)code * Ddim + l * 4];
        *(float4*)&out[(size_t)row * Ddim + l * 4] = q4;
        const double dx = (double)(q4.x - x4.x), dy = (double)(q4.y - x4.y);
        const double dz = (double)(q4.z - x4.z), dw = (double)(q4.w - x4.w);
        lacc += dx * dx + dy * dy + dz * dz + dw * dw;
    }
    #pragma unroll
    for (int off = 32; off; off >>= 1) lacc += __shfl_down(lacc, off, 64);
    if (l == 0) lred[w] = lacc;
    __syncthreads();
    if (t == 0)
        partials[blockIdx.x] = lred[0] + lred[1] + lred[2] + lred[3];
}

// ---- final loss ----
__global__ __launch_bounds__(256)
void vq_lossk(const double* __restrict__ partials, float* __restrict__ lossOut) {
    __shared__ double red[4];
    double v = 0.0;
    for (int i = threadIdx.x; i < 512; i += 256) v += partials[i];
    #pragma unroll
    for (int off = 32; off; off >>= 1) v += __shfl_down(v, off, 64);
    const int lane = threadIdx.x & 63, grp = threadIdx.x >> 6;
    if (lane == 0) red[grp] = v;
    __syncthreads();
    if (threadIdx.x == 0)
        lossOut[0] = (float)(1.25 * (red[0] + red[1] + red[2] + red[3]) /
                             (double)((size_t)Mrows * Ddim));
}

// ===========================================================================
extern "C" void kernel_launch(void* const* d_in, const int* in_sizes, int n_in,
                              void* d_out, int out_size, void* d_ws, size_t ws_size,
                              hipStream_t stream) {
    const float* X = (const float*)d_in[0];
    const float* E = (const float*)d_in[1];
    float* out = (float*)d_out;
    char* ws = (char*)d_ws;

    // workspace: partials 4KB | ET 1MB | ETbf 512KB | norms 4KB  (~1.5MB)
    const size_t partB = 512 * 8;
    const size_t etB   = (size_t)Kcode * Ddim * 4;
    const size_t etbfB = (size_t)Kcode * Ddim * 2;
    char* p = ws;
    double* partials = (double*)p;  p += partB;
    float*  ET       = (float*)p;   p += etB;
    char*   ETbf     = p;           p += etbfB;
    float*  norms    = (float*)p;

    vq_prep<<<16, 256, 0, stream>>>(E, ET, ETbf, norms);
    vq_fused<<<Mrows / 64, 256, 0, stream>>>(X, ETbf, ET, norms, out, partials);
    vq_lossk<<<1, 256, 0, stream>>>(partials, out + (size_t)Mrows * Ddim);
}

// Round 17
// 80.582 us; speedup vs baseline: 3.0881x; 1.1038x over previous
//
#include <hip/hip_runtime.h>

// ---------------------------------------------------------------------------
// VectorQuantizer R17: R8/R16 structure with HALVED phase count.
// R16 control reproduced R8 exactly (88.94us) -> environment stable, all
// prior regressions real. Packing ledger: configs whose LDS allows >2
// blocks/CU regress (uneven packing straggler round); R17 keeps capacity
// EXACTLY 2 (78.8KB: 2x fits 160KB, 3x doesn't).
// Change vs R16: 16 phases x 64 codes (32KB chunks, 4 groups/phase) instead
// of 32 x 32 -- fixed per-phase overhead (barrier + chain ramp) halves,
// total work constant. CAP 32->16 to fit LDS; overflow (P ~ 0) handled by
// the verified bounded lane-parallel full scan.
// Exactness: unchanged (margin superset + exact fp32 rescore + tie-break).
// ---------------------------------------------------------------------------

constexpr int Mrows = 32768;
constexpr int Ddim  = 256;
constexpr int Kcode = 1024;

constexpr int   CAP    = 16;     // overflow (n>16) -> bounded full scan
constexpr float MARGIN = 0.25f;

typedef unsigned long long u64;
typedef unsigned short ushort_t;
typedef __attribute__((ext_vector_type(8))) short bf16x8;
typedef __attribute__((ext_vector_type(4))) float f32x4;

__device__ inline u64 packKey(float v, int idx) {
    unsigned u = __float_as_uint(v);
    u = (u & 0x80000000u) ? ~u : (u | 0x80000000u);   // order-preserving
    return ((u64)u << 32) | (unsigned)idx;
}
__device__ inline float unpackScore(u64 k) {
    unsigned v = (unsigned)(k >> 32);
    unsigned orig = (v & 0x80000000u) ? (v ^ 0x80000000u) : ~v;
    return __uint_as_float(orig);
}
__device__ inline ushort_t f2bf(float f) {   // RTN-even
    unsigned u = __float_as_uint(f);
    return (ushort_t)((u + 0x7fffu + ((u >> 16) & 1u)) >> 16);
}
__device__ inline void gload_lds16(const void* g, void* l) {
    __builtin_amdgcn_global_load_lds(
        (const __attribute__((address_space(1))) unsigned int*)g,
        (__attribute__((address_space(3))) unsigned int*)l, 16, 0, 0);
}

// ---- prep: block c handles codes [c*64, c*64+64)  (verified R4-R16) ----
__global__ __launch_bounds__(256)
void vq_prep(const float* __restrict__ E, float* __restrict__ ET,
             char* __restrict__ ETbf, float* __restrict__ norms) {
    __shared__ float tile[256][64];   // [k][code_local]
    const int t = threadIdx.x;
    const int c = blockIdx.x;

    #pragma unroll
    for (int i = 0; i < 16; ++i) {
        const int k = i * 16 + (t >> 4);
        *(float4*)&tile[k][(t & 15) * 4] =
            *(const float4*)&E[(size_t)k * Kcode + c * 64 + (t & 15) * 4];
    }
    __syncthreads();

    if (t < 64) {
        float s = 0.f;
        for (int k = 0; k < 256; ++k) s = fmaf(tile[k][t], tile[k][t], s);
        norms[c * 64 + t] = s;
    }
    #pragma unroll
    for (int j = 0; j < 16; ++j) {
        const int cl = t >> 2, k0 = (t & 3) * 64 + j * 4;
        float4 v = {tile[k0][cl], tile[k0 + 1][cl], tile[k0 + 2][cl], tile[k0 + 3][cl]};
        *(float4*)&ET[(size_t)(c * 64 + cl) * Ddim + k0] = v;
    }
    // ETbf fragment-linear: group G (16 codes) at byte G*8192 + s*1024 + l*16;
    // lane l: code = G*16 + (l&15), k = s*32 + (l>>4)*8 .. +8
    #pragma unroll
    for (int i = 0; i < 8; ++i) {
        const int wd = i * 256 + t;
        const int g = wd >> 9, s = (wd >> 6) & 7, l = wd & 63;
        const int cl = g * 16 + (l & 15);
        const int k0 = s * 32 + (l >> 4) * 8;
        union { uint4 v; ushort_t u[8]; } pk;
        #pragma unroll
        for (int j = 0; j < 8; ++j) pk.u[j] = f2bf(tile[k0 + j][cl]);
        *(uint4*)(ETbf + (size_t)c * 32768 + (size_t)wd * 16) = pk.v;
    }
}

// ---- fused: 64 rows x all 1024 codes per block; 16 phases of 64 codes ----
__global__ __launch_bounds__(256, 2)
void vq_fused(const float* __restrict__ X, const char* __restrict__ ETbf,
              const float* __restrict__ ET, const float* __restrict__ norms,
              float* __restrict__ out, double* __restrict__ partials) {
    __shared__ __align__(16) char smB[2][32768];   // 64 codes x 256 dims bf16
    __shared__ float    nrmS[1024];
    __shared__ u64      candS[64][CAP];
    __shared__ int      cntS[64];
    __shared__ unsigned escS[64];
    __shared__ float    rowminS[64];
    __shared__ double   lred[4];
    // LDS: 65536+4096+8192+256+256+256+32 = 78624 B -> capacity EXACTLY 2/CU

    const int t = threadIdx.x;
    const int l = t & 63;
    const int w = t >> 6;
    const int l15 = l & 15, lq = l >> 4;
    const int row0 = blockIdx.x * 64;

    if (t < 64) { cntS[t] = 0; escS[t] = 0; }
    #pragma unroll
    for (int i = 0; i < 4; ++i) nrmS[i * 256 + t] = norms[i * 256 + t];

    // ---- A fragments: wave w owns rows [row0 + w*16, +16)  (32 VGPRs) ----
    bf16x8 afrag[8];
    #pragma unroll
    for (int s = 0; s < 8; ++s) {
        const float* xp = X + (size_t)(row0 + w * 16 + l15) * Ddim
                          + s * 32 + lq * 8;
        const float4 v0 = *(const float4*)xp;
        const float4 v1 = *(const float4*)(xp + 4);
        union { bf16x8 v; ushort_t u[8]; } pk;
        pk.u[0] = f2bf(v0.x); pk.u[1] = f2bf(v0.y);
        pk.u[2] = f2bf(v0.z); pk.u[3] = f2bf(v0.w);
        pk.u[4] = f2bf(v1.x); pk.u[5] = f2bf(v1.y);
        pk.u[6] = f2bf(v1.z); pk.u[7] = f2bf(v1.w);
        afrag[s] = pk.v;
    }

    // per-lane top-3 tracking (values; indices only for top-2)
    float b1v[4], b2v[4], b3v[4];
    int   b1i[4], b2i[4];
    #pragma unroll
    for (int r = 0; r < 4; ++r) {
        b1v[r] = 3.4e38f; b2v[r] = 3.4e38f; b3v[r] = 3.4e38f;
        b1i[r] = 0; b2i[r] = 0;
    }

    auto STAGE = [&](int c, int buf) {
        const char* src = ETbf + ((size_t)c << 15);
        #pragma unroll
        for (int i = 0; i < 8; ++i)
            gload_lds16(src + (size_t)((i * 256 + t) << 4),
                        smB[buf] + ((i * 256 + (t & ~63)) << 4));
    };

    auto COMPUTE = [&](int c, int buf) {
        #pragma unroll
        for (int g = 0; g < 4; ++g) {
            const char* base = smB[buf] + g * 8192 + l * 16;
            bf16x8 b[8];
            #pragma unroll
            for (int s = 0; s < 8; ++s) b[s] = *(const bf16x8*)(base + s * 1024);
            f32x4 a0 = {0.f, 0.f, 0.f, 0.f}, a1 = {0.f, 0.f, 0.f, 0.f};
            #pragma unroll
            for (int s = 0; s < 8; s += 2) {     // two independent chains
                a0 = __builtin_amdgcn_mfma_f32_16x16x32_bf16(afrag[s], b[s], a0, 0, 0, 0);
                a1 = __builtin_amdgcn_mfma_f32_16x16x32_bf16(afrag[s + 1], b[s + 1], a1, 0, 0, 0);
            }
            const int code = c * 64 + g * 16 + l15;
            const float nk = nrmS[code];
            #pragma unroll
            for (int r = 0; r < 4; ++r) {
                const float sc = fmaf(-2.f, a0[r] + a1[r], nk);
                if (sc < b1v[r]) {
                    b3v[r] = b2v[r]; b2v[r] = b1v[r]; b2i[r] = b1i[r];
                    b1v[r] = sc; b1i[r] = code;
                } else if (sc < b2v[r]) {
                    b3v[r] = b2v[r]; b2v[r] = sc; b2i[r] = code;
                } else if (sc < b3v[r]) {
                    b3v[r] = sc;
                }
            }
        }
    };

    // ---- chunk pipeline: 16 chunks of 64 codes, double-buffered ----
    STAGE(0, 0);
    __syncthreads();
    for (int c = 0; c < 16; ++c) {
        if (c < 15) STAGE(c + 1, (c + 1) & 1);
        COMPUTE(c, c & 1);
        __syncthreads();
    }

    // ---- emission with FINAL block threshold ----
    #pragma unroll
    for (int r = 0; r < 4; ++r) {
        float m = b1v[r];
        #pragma unroll
        for (int off = 1; off < 16; off <<= 1)
            m = fminf(m, __shfl_xor(m, off, 16));
        const int rowL = w * 16 + lq * 4 + r;
        if (l15 == 0) rowminS[rowL] = m;
        const float thr = m + MARGIN;
        if (b1v[r] <= thr) {
            const int p = atomicAdd(&cntS[rowL], 1);
            if (p < CAP) candS[rowL][p] = packKey(b1v[r], b1i[r]);
        }
        if (b2v[r] <= thr) {
            const int p = atomicAdd(&cntS[rowL], 1);
            if (p < CAP) candS[rowL][p] = packKey(b2v[r], b2i[r]);
        }
        if (b3v[r] <= thr)
            atomicOr(&escS[rowL], 1u << l15);   // lane may have dropped a 4th+
    }
    __syncthreads();

    // ---- resolve epilogue: wave handles its own 16 rows ----
    double lacc = 0.0;
    for (int rr = 0; rr < 16; ++rr) {
        const int rowL = w * 16 + rr;
        const int row = row0 + rowL;
        const float4 x4 = *(const float4*)&X[(size_t)row * Ddim + l * 4];
        const int n = cntS[rowL];
        const unsigned em = escS[rowL];

        // shuffle-parallel exact fp32 rescore (one code, all 64 lanes)
        auto rescoreS = [&](int code) -> float {
            const float4 e4 = *(const float4*)&ET[(size_t)code * Ddim + l * 4];
            float d = x4.x * e4.x;
            d = fmaf(x4.y, e4.y, d);
            d = fmaf(x4.z, e4.z, d);
            d = fmaf(x4.w, e4.w, d);
            #pragma unroll
            for (int off = 1; off < 64; off <<= 1) d += __shfl_xor(d, off, 64);
            return nrmS[code] - 2.f * d;
        };
        // per-lane serial exact fp32 score (lane-parallel over codes)
        auto laneDot = [&](int cd) -> float {
            const float* ep = ET + (size_t)cd * Ddim;
            const float* xp = X + (size_t)row * Ddim;
            float s0 = 0.f, s1 = 0.f, s2 = 0.f, s3 = 0.f;
            for (int d0 = 0; d0 < 64; ++d0) {
                const float4 e4 = *(const float4*)(ep + d0 * 4);
                const float4 xx = *(const float4*)(xp + d0 * 4);
                s0 = fmaf(xx.x, e4.x, s0); s1 = fmaf(xx.y, e4.y, s1);
                s2 = fmaf(xx.z, e4.z, s2); s3 = fmaf(xx.w, e4.w, s3);
            }
            return nrmS[cd] - 2.f * ((s0 + s1) + (s2 + s3));
        };

        int code;
        if (n == 1 && em == 0) {
            code = (int)(candS[rowL][0] & 0xffffffffu);   // provably the argmin
        } else if (n >= 1 && n <= CAP) {
            float bS = 3.4e38f; int bC = 0x7fffffff;
            for (int j = 0; j < n; ++j) {
                const int cd = (int)(candS[rowL][j] & 0xffffffffu);
                const float s = rescoreS(cd);
                if (s < bS || (s == bS && cd < bC)) { bS = s; bC = cd; }
            }
            unsigned m2 = em;
            while (m2) {   // escalated lane: rescan its 64 codes, lane-parallel
                const int c15 = __ffs(m2) - 1; m2 &= m2 - 1;
                const int cd = l * 16 + c15;
                u64 k = packKey(laneDot(cd), cd);
                #pragma unroll
                for (int off = 1; off < 64; off <<= 1) {
                    const u64 o = __shfl_xor(k, off, 64);
                    if (o < k) k = o;
                }
                const float s = unpackScore(k);
                const int cd2 = (int)(k & 0xffffffffu);
                if (s < bS || (s == bS && cd2 < bC)) { bS = s; bC = cd2; }
            }
            code = bC;
        } else {   // overflow (P ~ 0): bounded lane-parallel full scan
            u64 k = ~0ULL;
            for (int i = 0; i < 16; ++i) {
                const int cd = i * 64 + l;
                const u64 k2 = packKey(laneDot(cd), cd);
                if (k2 < k) k = k2;
            }
            #pragma unroll
            for (int off = 1; off < 64; off <<= 1) {
                const u64 o = __shfl_xor(k, off, 64);
                if (o < k) k = o;
            }
            code = (int)(k & 0xffffffffu);
        }

        const float4 q4 = *(const float4*)&ET[(size_t)code * Ddim + l * 4];
        *(float4*)&out[(size_t)row * Ddim + l * 4] = q4;
        const double dx = (double)(q4.x - x4.x), dy = (double)(q4.y - x4.y);
        const double dz = (double)(q4.z - x4.z), dw = (double)(q4.w - x4.w);
        lacc += dx * dx + dy * dy + dz * dz + dw * dw;
    }
    #pragma unroll
    for (int off = 32; off; off >>= 1) lacc += __shfl_down(lacc, off, 64);
    if (l == 0) lred[w] = lacc;
    __syncthreads();
    if (t == 0)
        partials[blockIdx.x] = lred[0] + lred[1] + lred[2] + lred[3];
}

// ---- final loss ----
__global__ __launch_bounds__(256)
void vq_lossk(const double* __restrict__ partials, float* __restrict__ lossOut) {
    __shared__ double red[4];
    double v = 0.0;
    for (int i = threadIdx.x; i < 512; i += 256) v += partials[i];
    #pragma unroll
    for (int off = 32; off; off >>= 1) v += __shfl_down(v, off, 64);
    const int lane = threadIdx.x & 63, grp = threadIdx.x >> 6;
    if (lane == 0) red[grp] = v;
    __syncthreads();
    if (threadIdx.x == 0)
        lossOut[0] = (float)(1.25 * (red[0] + red[1] + red[2] + red[3]) /
                             (double)((size_t)Mrows * Ddim));
}

// ===========================================================================
extern "C" void kernel_launch(void* const* d_in, const int* in_sizes, int n_in,
                              void* d_out, int out_size, void* d_ws, size_t ws_size,
                              hipStream_t stream) {
    const float* X = (const float*)d_in[0];
    const float* E = (const float*)d_in[1];
    float* out = (float*)d_out;
    char* ws = (char*)d_ws;

    // workspace: partials 4KB | ET 1MB | ETbf 512KB | norms 4KB  (~1.5MB)
    const size_t partB = 512 * 8;
    const size_t etB   = (size_t)Kcode * Ddim * 4;
    const size_t etbfB = (size_t)Kcode * Ddim * 2;
    char* p = ws;
    double* partials = (double*)p;  p += partB;
    float*  ET       = (float*)p;   p += etB;
    char*   ETbf     = p;           p += etbfB;
    float*  norms    = (float*)p;

    vq_prep<<<16, 256, 0, stream>>>(E, ET, ETbf, norms);
    vq_fused<<<Mrows / 64, 256, 0, stream>>>(X, ETbf, ET, norms, out, partials);
    vq_lossk<<<1, 256, 0, stream>>>(partials, out + (size_t)Mrows * Ddim);
}